// Round 3
// baseline (208.551 us; speedup 1.0000x reference)
//
#include <hip/hip_runtime.h>
#include <math.h>

typedef unsigned int uint;
typedef unsigned long long u64;

#define NT 256
#define KTOP 200
#define CAP1 384     // per-quarter candidate cap (B1)
#define CAP2 256     // merged candidate cap (B2) == NT for the sort
#define NCLS 21      // total classes incl background
#define QKEYS 6148   // max scalar keys per quarter (1536*4 + tail + pad)

__device__ __forceinline__ uint f32_key(float f) {
  uint u = __float_as_uint(f);
  return (u & 0x80000000u) ? ~u : (u | 0x80000000u);
}

__device__ __forceinline__ u64 flip64(double d) {
  u64 u = (u64)__double_as_longlong(d);
  return (u & 0x8000000000000000ULL) ? ~u : (u | 0x8000000000000000ULL);
}

__device__ __forceinline__ double unflip64(u64 k) {
  u64 u = (k & 0x8000000000000000ULL) ? (k ^ 0x8000000000000000ULL) : ~k;
  return __longlong_as_double((long long)u);
}

// ---------------- Kernel A: decode boxes + f64 LSE + per-class sortable keys ----
__global__ __launch_bounds__(NT) void prep_kernel(
    const float* __restrict__ bboxes,   // [B,4,N]
    const float* __restrict__ scores,   // [B,21,N]
    const float* __restrict__ dboxes,   // [N,4]
    const float* __restrict__ conf_th,  // [20]
    const float* __restrict__ scale_xy_p,
    const float* __restrict__ scale_wh_p,
    float4* __restrict__ boxes_out,     // [B*N]
    double* __restrict__ lse_out,       // [B*N]
    uint*  __restrict__ keys_out,       // [B,20,N]
    int B, int N)
{
  __shared__ double s_logth[NCLS - 1];
  if (threadIdx.x < NCLS - 1) s_logth[threadIdx.x] = log((double)conf_th[threadIdx.x]);
  __syncthreads();

  int gid = blockIdx.x * blockDim.x + threadIdx.x;
  int total = B * N;
  if (gid >= total) return;
  int b = gid / N;
  int n = gid - b * N;

  float sxy = *scale_xy_p, swh = *scale_wh_p;

  const float* bb = bboxes + (size_t)b * 4 * N + n;
  float bx = bb[0];
  float by = bb[(size_t)N];
  float bw = bb[2 * (size_t)N];
  float bh = bb[3 * (size_t)N];
  float4 d = reinterpret_cast<const float4*>(dboxes)[n];  // cx,cy,w,h
  float x = sxy * bx * d.z + d.x;
  float y = sxy * by * d.w + d.y;
  float w = expf(swh * bw) * d.z;
  float h = expf(swh * bh) * d.w;
  boxes_out[gid] = make_float4(x - 0.5f * w, y - 0.5f * h, x + 0.5f * w, y + 0.5f * h);

  const float* sc = scores + (size_t)b * NCLS * N + n;
  float v[NCLS];
  float mx = -INFINITY;
#pragma unroll
  for (int c = 0; c < NCLS; ++c) { v[c] = sc[(size_t)c * N]; mx = fmaxf(mx, v[c]); }
  double sum = 0.0;
#pragma unroll
  for (int c = 0; c < NCLS; ++c) sum += exp((double)(v[c] - mx));
  double lse = (double)mx + log(sum);
  lse_out[gid] = lse;

#pragma unroll
  for (int c = 0; c < NCLS - 1; ++c) {
    double s = (double)v[c + 1] - lse;
    uint key = 0;
    if (s > s_logth[c]) key = f32_key((float)s);
    keys_out[((size_t)b * (NCLS - 1) + c) * N + n] = key;
  }
}

// ---------------- Kernel B1: per (b,class,quarter) ties-safe top>=200 ---------
// Collects all keys >= L (bin-granular, count >= min(200, valid)) of its
// quarter; writes packed (key<<32|idx) candidates into its OWN quarter region
// of the keys row (safe: keys staged to LDS first, row only read by this task).
__global__ __launch_bounds__(NT) void select_part1(
    uint* __restrict__ keys,   // [B*20, N] (candidates written back in place)
    uint* __restrict__ cnts,   // [B*20*4]
    int N)
{
  int task = blockIdx.x >> 2;
  int q = blockIdx.x & 3;
  int tid = threadIdx.x;
  int lane = tid & 63;
  uint* krow = keys + (size_t)task * N;

  int N4 = N >> 2;
  int QS4 = (N4 + 3) >> 2;
  int s4 = q * QS4;
  int e4 = min(N4, s4 + QS4);
  int nk4 = max(e4 - s4, 0);
  int base = s4 << 2;
  int nk = nk4 << 2;
  int tail = (q == 3) ? (N & 3) : 0;
  int ntot = nk + tail;

  __shared__ uint4 skeys4[(QKEYS + 3) / 4];
  uint* skeys = (uint*)skeys4;
  __shared__ uint hist[256];
  __shared__ uint sTot, sCnt, sL, sPref, sAbove, sRank;
  __shared__ int sNeed;

  hist[tid] = 0;
  if (tid == 0) { sTot = 0; sCnt = 0; sNeed = 0; sL = 1u; }
  __syncthreads();

  // ---- stage to LDS + level-0 hist (key>>24) with wave-aggregated atomics
  uint lv = 0;
  const uint4* g4 = reinterpret_cast<const uint4*>(krow) + s4;
  for (int i = tid; i < nk4; i += NT) {
    uint4 kv = g4[i];
    ((uint4*)skeys)[i] = kv;
#pragma unroll
    for (int comp = 0; comp < 4; ++comp) {
      uint k = (comp == 0) ? kv.x : (comp == 1) ? kv.y : (comp == 2) ? kv.z : kv.w;
      uint bin = k >> 24;
      bool val = (k != 0);
      lv += val ? 1u : 0u;
      u64 act = __ballot(val);
      while (act) {
        int ldr = __ffsll(act) - 1;
        uint lb = (uint)__shfl((int)bin, ldr);
        u64 same = __ballot(val && bin == lb);
        if (lane == ldr) atomicAdd(&hist[lb], (uint)__popcll(same));
        act &= ~same;
      }
    }
  }
  for (int t = nk + tid; t < ntot; t += NT) {
    uint k = krow[base + t];
    skeys[t] = k;
    if (k) { atomicAdd(&hist[k >> 24], 1u); lv++; }
  }
  for (int off = 32; off; off >>= 1) lv += __shfl_down(lv, off);
  if (lane == 0) atomicAdd(&sTot, lv);
  __syncthreads();

  // ---- level-0 walk
  if (tid == 0) {
    uint tot = sTot;
    if (tot < KTOP) {
      sL = 1u; sNeed = 0;          // take all valid
    } else {
      uint cum = 0; int bin = 255;
      for (int j = 255; j >= 0; --j) { cum += hist[j]; if (cum >= KTOP) { bin = j; break; } }
      uint above = cum - hist[bin];
      if (cum <= CAP1) { sL = ((uint)bin) << 24; sNeed = 0; }
      else { sNeed = 1; sPref = (uint)bin; sAbove = above; sRank = KTOP - above; }
    }
  }
  __syncthreads();

  // ---- refine levels over bits [23:16],[15:8],[7:0] (from LDS, spread bins)
  for (int lvl = 0; lvl < 3; ++lvl) {
    bool active = (sNeed != 0);   // uniform
    __syncthreads();
    if (active) {
      int shift = (lvl == 0) ? 16 : (lvl == 1) ? 8 : 0;
      int pshift = shift + 8;
      hist[tid] = 0;
      __syncthreads();
      uint pref = sPref;
      for (int i = tid; i < nk4; i += NT) {
        uint4 kv = ((const uint4*)skeys)[i];
        if (kv.x && (kv.x >> pshift) == pref) atomicAdd(&hist[(kv.x >> shift) & 255u], 1u);
        if (kv.y && (kv.y >> pshift) == pref) atomicAdd(&hist[(kv.y >> shift) & 255u], 1u);
        if (kv.z && (kv.z >> pshift) == pref) atomicAdd(&hist[(kv.z >> shift) & 255u], 1u);
        if (kv.w && (kv.w >> pshift) == pref) atomicAdd(&hist[(kv.w >> shift) & 255u], 1u);
      }
      for (int t = nk + tid; t < ntot; t += NT) {
        uint k = skeys[t];
        if (k && (k >> pshift) == pref) atomicAdd(&hist[(k >> shift) & 255u], 1u);
      }
      __syncthreads();
      if (tid == 0) {
        uint rank = sRank, above = sAbove;
        uint cum = 0; int bin = 255;
        for (int j = 255; j >= 0; --j) { cum += hist[j]; if (cum >= rank) { bin = j; break; } }
        uint cnt_ge = above + cum;
        uint npref = (pref << 8) | (uint)bin;
        sL = npref << shift;
        if (cnt_ge <= CAP1 || shift == 0) sNeed = 0;
        else { sPref = npref; sAbove = cnt_ge - hist[bin]; sRank = rank - (cum - hist[bin]); }
      }
      __syncthreads();
    }
  }
  __syncthreads();

  // ---- collect (key >= L) -> packed u64 into own global quarter region
  uint L = sL;
  u64* cand = reinterpret_cast<u64*>(krow + base);
  for (int i = tid; i < nk4; i += NT) {
    uint4 kv = ((const uint4*)skeys)[i];
    int sb = base + (i << 2);
    if (kv.x >= L) { uint p = atomicAdd(&sCnt, 1u); if (p < CAP1) cand[p] = ((u64)kv.x << 32) | (uint)(sb    ); }
    if (kv.y >= L) { uint p = atomicAdd(&sCnt, 1u); if (p < CAP1) cand[p] = ((u64)kv.y << 32) | (uint)(sb + 1); }
    if (kv.z >= L) { uint p = atomicAdd(&sCnt, 1u); if (p < CAP1) cand[p] = ((u64)kv.z << 32) | (uint)(sb + 2); }
    if (kv.w >= L) { uint p = atomicAdd(&sCnt, 1u); if (p < CAP1) cand[p] = ((u64)kv.w << 32) | (uint)(sb + 3); }
  }
  for (int t = nk + tid; t < ntot; t += NT) {
    uint k = skeys[t];
    if (k >= L) { uint p = atomicAdd(&sCnt, 1u); if (p < CAP1) cand[p] = ((u64)k << 32) | (uint)(base + t); }
  }
  __syncthreads();
  if (tid == 0) cnts[blockIdx.x] = min(sCnt, (uint)CAP1);
}

// ---------------- Kernel B2: merge quarters, exact top-200, NMS, output -------
__global__ __launch_bounds__(NT) void select_part2(
    const uint* __restrict__ keys, const uint* __restrict__ cnts,
    const float* __restrict__ scores, const double* __restrict__ lse,
    const float4* __restrict__ boxesws, const float* __restrict__ nms_th_p,
    float* __restrict__ out, int B, int N)
{
  const int C1 = NCLS - 1;
  int task = blockIdx.x;
  int b = task / C1, c = task - b * C1;
  int tid = threadIdx.x;
  int N4 = N >> 2;
  int QS4 = (N4 + 3) >> 2;

  __shared__ u64 cl[4 * CAP1];
  __shared__ uint hist[256];
  __shared__ uint scq[4], soq[4];
  __shared__ uint sTot, sCnt, sL, sPref, sAbove, sRank;
  __shared__ int sNeed;
  __shared__ u64 skey[CAP2];
  __shared__ int si[CAP2];
  __shared__ float bl[KTOP], bt[KTOP], br_[KTOP], bb_[KTOP];
  __shared__ double sarea[KTOP];
  __shared__ u64 smask[KTOP][4];
  __shared__ u64 saliveW[4];

  if (tid < 4) scq[tid] = cnts[task * 4 + tid];
  hist[tid] = 0;
  if (tid == 0) { sCnt = 0; sNeed = 0; sL = 1u; }
  __syncthreads();
  if (tid == 0) {
    uint o = 0;
    for (int qq = 0; qq < 4; ++qq) { soq[qq] = o; o += scq[qq]; }
    sTot = o;
  }
  __syncthreads();

  uint total = sTot;
  const uint* krow = keys + (size_t)task * N;
  for (int qq = 0; qq < 4; ++qq) {
    const u64* cq = reinterpret_cast<const u64*>(krow + (size_t)qq * (QS4 << 2));
    uint cnq = scq[qq], off = soq[qq];
    for (int j = tid; j < (int)cnq; j += NT) cl[off + j] = cq[j];
  }
  __syncthreads();

  uint cnt;
  if (total <= CAP2) {
    for (int p = tid; p < (int)total; p += NT) si[p] = (int)(uint)cl[p];
    cnt = total;
  } else {
    // radix rank-200 over hi-32 keys in LDS
    for (int i = tid; i < (int)total; i += NT) atomicAdd(&hist[(uint)(cl[i] >> 56)], 1u);
    __syncthreads();
    if (tid == 0) {
      uint cum = 0; int bin = 255;
      for (int j = 255; j >= 0; --j) { cum += hist[j]; if (cum >= KTOP) { bin = j; break; } }
      uint above = cum - hist[bin];
      if (cum <= CAP2) { sL = ((uint)bin) << 24; sNeed = 0; }
      else { sNeed = 1; sPref = (uint)bin; sAbove = above; sRank = KTOP - above; }
    }
    __syncthreads();
    for (int lvl = 0; lvl < 3; ++lvl) {
      bool active = (sNeed != 0);
      __syncthreads();
      if (active) {
        int shift = (lvl == 0) ? 16 : (lvl == 1) ? 8 : 0;
        int pshift = shift + 8;
        hist[tid] = 0;
        __syncthreads();
        uint pref = sPref;
        for (int i = tid; i < (int)total; i += NT) {
          uint k = (uint)(cl[i] >> 32);
          if ((k >> pshift) == pref) atomicAdd(&hist[(k >> shift) & 255u], 1u);
        }
        __syncthreads();
        if (tid == 0) {
          uint rank = sRank, above = sAbove;
          uint cum = 0; int bin = 255;
          for (int j = 255; j >= 0; --j) { cum += hist[j]; if (cum >= rank) { bin = j; break; } }
          uint cnt_ge = above + cum;
          uint npref = (pref << 8) | (uint)bin;
          sL = npref << shift;
          if (cnt_ge <= CAP2 || shift == 0) sNeed = 0;
          else { sPref = npref; sAbove = cnt_ge - hist[bin]; sRank = rank - (cum - hist[bin]); }
        }
        __syncthreads();
      }
    }
    uint L = sL;
    for (int i = tid; i < (int)total; i += NT) {
      u64 e = cl[i];
      uint k = (uint)(e >> 32);
      if (k >= L) { uint p = atomicAdd(&sCnt, 1u); if (p < CAP2) si[p] = (int)(uint)e; }
    }
    __syncthreads();
    cnt = min(sCnt, (uint)CAP2);
  }
  __syncthreads();

  // ---- exact f64 scores, pad, sort CAP2 by (score desc, idx asc)
  for (int p = tid; p < CAP2; p += NT) {
    if (p < (int)cnt) {
      int n = si[p];
      double s = (double)scores[((size_t)b * NCLS + (c + 1)) * N + n] - lse[(size_t)b * N + n];
      skey[p] = flip64(s);
    } else { skey[p] = 0ULL; si[p] = 0x7FFFFFFF; }
  }
  __syncthreads();

  for (int kk = 2; kk <= CAP2; kk <<= 1) {
    for (int jj = kk >> 1; jj > 0; jj >>= 1) {
      int i = tid;                 // CAP2 == NT: one element per thread
      int l = i ^ jj;
      if (l > i) {
        u64 k_i = skey[i], k_l = skey[l];
        int i_i = si[i], i_l = si[l];
        bool before_il = (k_i > k_l) || (k_i == k_l && i_i < i_l);
        bool dirAsc = ((i & kk) == 0);
        bool sw = dirAsc ? !before_il : before_il;
        if (sw) { skey[i] = k_l; skey[l] = k_i; si[i] = i_l; si[l] = i_i; }
      }
      __syncthreads();
    }
  }

  int valid_cnt = (int)min(cnt, (uint)KTOP);

  if (tid < KTOP) {
    bool v = tid < valid_cnt;
    float4 bx = v ? boxesws[(size_t)b * N + si[tid]] : make_float4(0.f, 0.f, 0.f, 0.f);
    bl[tid] = bx.x; bt[tid] = bx.y; br_[tid] = bx.z; bb_[tid] = bx.w;
    double w = fmax((double)bx.z - (double)bx.x, 0.0);
    double h = fmax((double)bx.w - (double)bx.y, 0.0);
    sarea[tid] = w * h;
  }
  __syncthreads();

  double nth = (double)(*nms_th_p);

  // ---- 200x200 suppression bitmask (parallel)
  for (int u = tid; u < KTOP * 4; u += NT) {
    int i = u >> 2, w = u & 3;
    u64 m = 0;
    if (i < valid_cnt) {
      int j0 = max(i + 1, w * 64);
      int j1 = min(valid_cnt, w * 64 + 64);
      double li = (double)bl[i], ti = (double)bt[i];
      double ri = (double)br_[i], bi = (double)bb_[i];
      double ai = sarea[i];
      for (int j = j0; j < j1; ++j) {
        double xx1 = fmax(li, (double)bl[j]);
        double yy1 = fmax(ti, (double)bt[j]);
        double xx2 = fmin(ri, (double)br_[j]);
        double yy2 = fmin(bi, (double)bb_[j]);
        double ww = fmax(xx2 - xx1, 0.0), hh = fmax(yy2 - yy1, 0.0);
        double inter = ww * hh;
        double iou = inter / (ai + sarea[j] - inter + 1e-9);
        if (iou >= nth) m |= 1ULL << (j - w * 64);
      }
    }
    smask[i][w] = m;
  }
  __syncthreads();

  // ---- greedy resolve in one wave, no barriers
  if (tid < 64) {
    u64 aw = 0;
    if (tid < 4) {
      int lo = tid * 64;
      int nb = valid_cnt - lo;
      nb = nb < 0 ? 0 : (nb > 64 ? 64 : nb);
      aw = (nb == 64) ? ~0ULL : ((nb > 0) ? ((1ULL << nb) - 1ULL) : 0ULL);
    }
    for (int i = 0; i < valid_cnt; ++i) {
      u64 wa = __shfl(aw, i >> 6);
      if ((wa >> (i & 63)) & 1ULL) {
        if (tid < 4) aw &= ~smask[i][tid];
      }
    }
    if (tid < 4) saliveW[tid] = aw;
  }
  __syncthreads();

  // ---- outputs: boxes | labels | scores | keep
  size_t M = (size_t)C1 * KTOP;
  float* out_boxes  = out;
  float* out_labels = out + (size_t)B * M * 4;
  float* out_scores = out_labels + (size_t)B * M;
  float* out_keep   = out_scores + (size_t)B * M;
  if (tid < KTOP) {
    size_t slot = ((size_t)b * C1 + c) * KTOP + tid;
    bool kept = (tid < valid_cnt) && ((saliveW[tid >> 6] >> (tid & 63)) & 1ULL);
    float4 bx = kept ? make_float4(bl[tid], bt[tid], br_[tid], bb_[tid])
                     : make_float4(0.f, 0.f, 0.f, 0.f);
    reinterpret_cast<float4*>(out_boxes)[slot] = bx;
    out_labels[slot] = kept ? (float)(c + 1) : 0.0f;
    out_scores[slot] = kept ? (float)exp(unflip64(skey[tid])) : 0.0f;
    out_keep[slot]   = kept ? 1.0f : 0.0f;
  }
}

extern "C" void kernel_launch(void* const* d_in, const int* in_sizes, int n_in,
                              void* d_out, int out_size, void* d_ws, size_t ws_size,
                              hipStream_t stream) {
  const float* bboxes   = (const float*)d_in[0];   // [B,4,N]
  const float* scores   = (const float*)d_in[1];   // [B,21,N]
  const float* dboxes   = (const float*)d_in[2];   // [1,N,4]
  const float* conf_th  = (const float*)d_in[3];   // [20]
  const float* nms_th   = (const float*)d_in[4];   // scalar
  const float* scale_xy = (const float*)d_in[6];   // scalar
  const float* scale_wh = (const float*)d_in[7];   // scalar

  int N = in_sizes[2] / 4;
  int B = in_sizes[0] / (4 * N);
  const int C1 = NCLS - 1;

  // workspace layout: lse (f64) | boxes (float4) | keys (u32) | cnts (u32)
  char* ws = (char*)d_ws;
  double* lse     = (double*)ws;
  float4* boxesws = (float4*)(ws + (size_t)B * N * 8);
  uint*   keys    = (uint*)  (ws + (size_t)B * N * 8 + (size_t)B * N * 16);
  uint*   cnts    = (uint*)  (ws + (size_t)B * N * 8 + (size_t)B * N * 16
                                 + (size_t)B * C1 * N * 4);

  int total = B * N;
  int blocksA = (total + NT - 1) / NT;
  prep_kernel<<<blocksA, NT, 0, stream>>>(
      bboxes, scores, dboxes, conf_th, scale_xy, scale_wh,
      boxesws, lse, keys, B, N);

  select_part1<<<B * C1 * 4, NT, 0, stream>>>(keys, cnts, N);

  select_part2<<<B * C1, NT, 0, stream>>>(
      keys, cnts, scores, lse, boxesws, nms_th, (float*)d_out, B, N);
}

// Round 4
// 168.226 us; speedup vs baseline: 1.2397x; 1.2397x over previous
//
#include <hip/hip_runtime.h>
#include <math.h>

typedef unsigned int uint;
typedef unsigned long long u64;

#define NT 256
#define KTOP 200
#define CAP 256      // candidate cap == NT (one per thread for rank-sort)
#define NCLS 21      // total classes incl background
#define MROWS 208    // smask rows (13 chunks of 16)

__device__ __forceinline__ uint f32_key(float f) {
  uint u = __float_as_uint(f);
  return (u & 0x80000000u) ? ~u : (u | 0x80000000u);
}

__device__ __forceinline__ u64 flip64(double d) {
  u64 u = (u64)__double_as_longlong(d);
  return (u & 0x8000000000000000ULL) ? ~u : (u | 0x8000000000000000ULL);
}

__device__ __forceinline__ double unflip64(u64 k) {
  u64 u = (k & 0x8000000000000000ULL) ? (k ^ 0x8000000000000000ULL) : ~k;
  return __longlong_as_double((long long)u);
}

// ---------------- Kernel A: decode boxes + f64 LSE + per-class sortable keys ----
__global__ __launch_bounds__(NT) void prep_kernel(
    const float* __restrict__ bboxes,   // [B,4,N]
    const float* __restrict__ scores,   // [B,21,N]
    const float* __restrict__ dboxes,   // [N,4]
    const float* __restrict__ conf_th,  // [20]
    const float* __restrict__ scale_xy_p,
    const float* __restrict__ scale_wh_p,
    float4* __restrict__ boxes_out,     // [B*N]
    double* __restrict__ lse_out,       // [B*N]
    uint*  __restrict__ keys_out,       // [B,20,N]
    int B, int N)
{
  __shared__ double s_logth[NCLS - 1];
  if (threadIdx.x < NCLS - 1) s_logth[threadIdx.x] = log((double)conf_th[threadIdx.x]);
  __syncthreads();

  int gid = blockIdx.x * blockDim.x + threadIdx.x;
  int total = B * N;
  if (gid >= total) return;
  int b = gid / N;
  int n = gid - b * N;

  float sxy = *scale_xy_p, swh = *scale_wh_p;

  const float* bb = bboxes + (size_t)b * 4 * N + n;
  float bx = bb[0];
  float by = bb[(size_t)N];
  float bw = bb[2 * (size_t)N];
  float bh = bb[3 * (size_t)N];
  float4 d = reinterpret_cast<const float4*>(dboxes)[n];  // cx,cy,w,h
  float x = sxy * bx * d.z + d.x;
  float y = sxy * by * d.w + d.y;
  float w = expf(swh * bw) * d.z;
  float h = expf(swh * bh) * d.w;
  boxes_out[gid] = make_float4(x - 0.5f * w, y - 0.5f * h, x + 0.5f * w, y + 0.5f * h);

  const float* sc = scores + (size_t)b * NCLS * N + n;
  float v[NCLS];
  float mx = -INFINITY;
#pragma unroll
  for (int c = 0; c < NCLS; ++c) { v[c] = sc[(size_t)c * N]; mx = fmaxf(mx, v[c]); }
  double sum = 0.0;
#pragma unroll
  for (int c = 0; c < NCLS; ++c) sum += exp((double)(v[c] - mx));
  double lse = (double)mx + log(sum);
  lse_out[gid] = lse;

#pragma unroll
  for (int c = 0; c < NCLS - 1; ++c) {
    double s = (double)v[c + 1] - lse;
    uint key = 0;
    if (s > s_logth[c]) key = f32_key((float)s);
    keys_out[((size_t)b * (NCLS - 1) + c) * N + n] = key;
  }
}

// ---------------- Kernel B: per (b,class) top-200 select + NMS + output --------
__global__ __launch_bounds__(NT) void select_nms_kernel(
    const uint*  __restrict__ keys,     // [B,20,N]
    const float* __restrict__ scores,   // [B,21,N]
    const double* __restrict__ lse,     // [B*N]
    const float4* __restrict__ boxesws, // [B*N]
    const float* __restrict__ nms_th_p,
    float* __restrict__ out,            // boxes | labels | scores | keep (flat)
    int B, int N)
{
  const int C1 = NCLS - 1;
  int task = blockIdx.x;
  int b = task / C1;
  int c = task - b * C1;
  int tid = threadIdx.x;
  int lane = tid & 63;
  const uint* krow = keys + ((size_t)b * C1 + c) * N;
  const uint4* krow4 = reinterpret_cast<const uint4*>(krow);
  int nv = N >> 2;

  __shared__ uint hist[4096];
  __shared__ int si[CAP];             // candidate idx (also psum scratch)
  __shared__ u64 skey[CAP];           // f64 flipped score keys (by slot)
  __shared__ u64 skid[CAP];           // sorted keys (by rank)
  __shared__ float bl[KTOP], bt[KTOP], br_[KTOP], bb_[KTOP];
  __shared__ double sarea[KTOP];
  __shared__ u64 smask[MROWS][4];
  __shared__ u64 saliveW[4];
  __shared__ uint sTot, sCnt, sL, sPref, sAbove, sRank;
  __shared__ int sNeed;

  for (int i = tid; i < 4096; i += NT) hist[i] = 0;
  if (tid == 0) { sTot = 0; sCnt = 0; sNeed = 0; sL = 1u; }
  __syncthreads();

  // ---- pass 1: histogram over top 12 key bits + valid count (uint4 loads)
  uint lv = 0;
  for (int i = tid; i < nv; i += NT) {
    uint4 k = krow4[i];
    if (k.x) { atomicAdd(&hist[k.x >> 20], 1u); lv++; }
    if (k.y) { atomicAdd(&hist[k.y >> 20], 1u); lv++; }
    if (k.z) { atomicAdd(&hist[k.z >> 20], 1u); lv++; }
    if (k.w) { atomicAdd(&hist[k.w >> 20], 1u); lv++; }
  }
  for (int n = (N & ~3) + tid; n < N; n += NT) {
    uint k = krow[n];
    if (k) { atomicAdd(&hist[k >> 20], 1u); lv++; }
  }
  for (int off = 32; off; off >>= 1) lv += __shfl_down(lv, off);
  if (lane == 0) atomicAdd(&sTot, lv);
  __syncthreads();

  // per-thread partial sums of 16 bins (scratch in si)
  {
    uint psum = 0;
    int base0 = tid * 16;
    for (int j = 0; j < 16; ++j) psum += hist[base0 + j];
    si[tid] = (int)psum;
  }
  __syncthreads();

  if (tid == 0) {
    uint tot = sTot;
    if (tot < KTOP) {
      sL = 1u; sNeed = 0;              // take all valid
    } else {
      uint run = 0; int seg = 0;
      for (int t = 255; t >= 0; --t) {
        uint ps = (uint)si[t];
        if (run + ps >= KTOP) { seg = t; break; }
        run += ps;
      }
      uint cum = run; int bin = seg * 16;
      for (int j = seg * 16 + 15; j >= seg * 16; --j) {
        cum += hist[j];
        if (cum >= KTOP) { bin = j; break; }
      }
      uint above = cum - hist[bin];
      if (cum <= CAP) { sL = ((uint)bin) << 20; sNeed = 0; }
      else { sNeed = 1; sPref = (uint)bin; sAbove = above; sRank = KTOP - above; }
    }
  }
  __syncthreads();

  // ---- refinement levels: bits [19:12], [11:4], [3:0]
  for (int lvl = 0; lvl < 3; ++lvl) {
    bool active = (sNeed != 0);   // uniform
    __syncthreads();
    if (active) {
      int nbins  = (lvl == 2) ? 16 : 256;
      int shift  = (lvl == 0) ? 12 : (lvl == 1) ? 4 : 0;
      int pshift = (lvl == 0) ? 20 : (lvl == 1) ? 12 : 4;
      if (tid < nbins) hist[tid] = 0;
      __syncthreads();
      uint pref = sPref;
      for (int i = tid; i < nv; i += NT) {
        uint4 kv = krow4[i];
        if ((kv.x >> pshift) == pref) atomicAdd(&hist[(kv.x >> shift) & (uint)(nbins - 1)], 1u);
        if ((kv.y >> pshift) == pref) atomicAdd(&hist[(kv.y >> shift) & (uint)(nbins - 1)], 1u);
        if ((kv.z >> pshift) == pref) atomicAdd(&hist[(kv.z >> shift) & (uint)(nbins - 1)], 1u);
        if ((kv.w >> pshift) == pref) atomicAdd(&hist[(kv.w >> shift) & (uint)(nbins - 1)], 1u);
      }
      for (int n = (N & ~3) + tid; n < N; n += NT) {
        uint k = krow[n];
        if ((k >> pshift) == pref) atomicAdd(&hist[(k >> shift) & (uint)(nbins - 1)], 1u);
      }
      __syncthreads();
      // 16-segment partial sums to shorten the serial walk
      if (nbins == 256 && tid < 16) {
        uint ps = 0;
        for (int j = 0; j < 16; ++j) ps += hist[tid * 16 + j];
        si[tid] = (int)ps;
      }
      __syncthreads();
      if (tid == 0) {
        uint rank = sRank, above = sAbove;
        uint cum = 0; int bin = nbins - 1;
        if (nbins == 256) {
          uint run = 0; int seg = 15;
          for (int t = 15; t >= 0; --t) {
            uint ps = (uint)si[t];
            if (run + ps >= rank) { seg = t; break; }
            run += ps;
          }
          cum = run; bin = seg * 16;
          for (int j = seg * 16 + 15; j >= seg * 16; --j) {
            cum += hist[j];
            if (cum >= rank) { bin = j; break; }
          }
        } else {
          for (int j = nbins - 1; j >= 0; --j) {
            cum += hist[j];
            if (cum >= rank) { bin = j; break; }
          }
        }
        uint cnt_ge = above + cum;
        uint npref = (pref << ((lvl == 2) ? 4 : 8)) | (uint)bin;
        sPref = npref;
        sL = npref << shift;
        if (cnt_ge <= CAP || shift == 0) sNeed = 0;
        else { sAbove = cnt_ge - hist[bin]; sRank = rank - (cum - hist[bin]); }
      }
      __syncthreads();
    }
  }
  __syncthreads();

  // ---- collect candidate indices with key >= L
  uint L = sL;
  for (int i = tid; i < nv; i += NT) {
    uint4 kv = krow4[i];
    int base = i << 2;
    if (kv.x >= L) { uint p = atomicAdd(&sCnt, 1u); if (p < CAP) si[p] = base; }
    if (kv.y >= L) { uint p = atomicAdd(&sCnt, 1u); if (p < CAP) si[p] = base + 1; }
    if (kv.z >= L) { uint p = atomicAdd(&sCnt, 1u); if (p < CAP) si[p] = base + 2; }
    if (kv.w >= L) { uint p = atomicAdd(&sCnt, 1u); if (p < CAP) si[p] = base + 3; }
  }
  for (int n = (N & ~3) + tid; n < N; n += NT) {
    uint k = krow[n];
    if (k >= L) { uint p = atomicAdd(&sCnt, 1u); if (p < CAP) si[p] = n; }
  }
  __syncthreads();
  uint cnt = min(sCnt, (uint)CAP);
  int valid_cnt = (int)min(cnt, (uint)KTOP);

  // ---- gather exact f64 scores; pad with unique low keys
  {
    int p = tid;
    if (p < (int)cnt) {
      int n = si[p];
      double s = (double)scores[((size_t)b * NCLS + (c + 1)) * N + n] - lse[(size_t)b * N + n];
      skey[p] = flip64(s);
    } else {
      skey[p] = 0ULL;
      si[p] = 0x40000000 + p;   // unique pad idx for total order
    }
  }
  __syncthreads();

  // ---- rank-sort: each thread computes exact rank of its slot (broadcast reads)
  {
    u64 kp = skey[tid];
    int ip = si[tid];
    int r = 0;
#pragma unroll 4
    for (int j = 0; j < CAP; ++j) {
      u64 kj = skey[j];
      int ij = si[j];
      r += ((kj > kp) || (kj == kp && ij < ip)) ? 1 : 0;
    }
    skid[r] = kp;
    if (tid < (int)cnt && r < KTOP) {
      float4 bx = boxesws[(size_t)b * N + ip];
      bl[r] = bx.x; bt[r] = bx.y; br_[r] = bx.z; bb_[r] = bx.w;
      double w = fmax((double)bx.z - (double)bx.x, 0.0);
      double h = fmax((double)bx.w - (double)bx.y, 0.0);
      sarea[r] = w * h;
    }
  }
  __syncthreads();

  double nth = (double)(*nms_th_p);

  // ---- 208x4-word suppression bitmask (rows >= valid_cnt zero-filled)
  for (int u = tid; u < MROWS * 4; u += NT) {
    int i = u >> 2, w = u & 3;
    u64 m = 0;
    if (i < valid_cnt) {
      int j0 = max(i + 1, w * 64);
      int j1 = min(valid_cnt, w * 64 + 64);
      double li = (double)bl[i], ti = (double)bt[i];
      double ri = (double)br_[i], bi = (double)bb_[i];
      double ai = sarea[i];
      for (int j = j0; j < j1; ++j) {
        double xx1 = fmax(li, (double)bl[j]);
        double yy1 = fmax(ti, (double)bt[j]);
        double xx2 = fmin(ri, (double)br_[j]);
        double yy2 = fmin(bi, (double)bb_[j]);
        double ww = fmax(xx2 - xx1, 0.0), hh = fmax(yy2 - yy1, 0.0);
        double inter = ww * hh;
        double iou = inter / (ai + sarea[j] - inter + 1e-9);
        if (iou >= nth) m |= 1ULL << (j - w * 64);
      }
    }
    smask[i][w] = m;
  }
  __syncthreads();

  // ---- greedy resolve: wave 0, masks preloaded to registers, pure VALU chain
  if (tid < 64) {
    // lane holds smask[c*16 + (lane>>2)][lane&3] for each chunk c
    int row = lane >> 2, col = lane & 3;
#define LOADM(c) u64 M##c = smask[(c)*16 + row][col];
    LOADM(0) LOADM(1) LOADM(2) LOADM(3) LOADM(4) LOADM(5) LOADM(6)
    LOADM(7) LOADM(8) LOADM(9) LOADM(10) LOADM(11) LOADM(12)
#undef LOADM
    int vc = valid_cnt;
    u64 aw0, aw1, aw2, aw3;
    {
      int n0 = vc, n1 = vc - 64, n2 = vc - 128, n3 = vc - 192;
      aw0 = (n0 >= 64) ? ~0ULL : ((n0 > 0) ? ((1ULL << n0) - 1) : 0ULL);
      aw1 = (n1 >= 64) ? ~0ULL : ((n1 > 0) ? ((1ULL << n1) - 1) : 0ULL);
      aw2 = (n2 >= 64) ? ~0ULL : ((n2 > 0) ? ((1ULL << n2) - 1) : 0ULL);
      aw3 = (n3 >= 64) ? ~0ULL : ((n3 > 0) ? ((1ULL << n3) - 1) : 0ULL);
    }
    u64 kp0 = 0, kp1 = 0, kp2 = 0, kp3 = 0;
#define GREEDY_CHUNK(c, AW, KP) { \
    uint fld = (uint)((AW >> (((c) & 3) * 16)) & 0xFFFFULL); \
    while (fld) { \
      int bi = __ffs(fld) - 1; \
      int slot = bi << 2; \
      u64 mw0 = __shfl(M##c, slot); \
      u64 mw1 = __shfl(M##c, slot + 1); \
      u64 mw2 = __shfl(M##c, slot + 2); \
      u64 mw3 = __shfl(M##c, slot + 3); \
      aw0 &= ~mw0; aw1 &= ~mw1; aw2 &= ~mw2; aw3 &= ~mw3; \
      KP |= 1ULL << (((c) & 3) * 16 + bi); \
      fld = ((uint)((AW >> (((c) & 3) * 16)) & 0xFFFFULL)) & (uint)(0xFFFFu << (bi + 1)); \
    } }
    GREEDY_CHUNK(0, aw0, kp0) GREEDY_CHUNK(1, aw0, kp0)
    GREEDY_CHUNK(2, aw0, kp0) GREEDY_CHUNK(3, aw0, kp0)
    GREEDY_CHUNK(4, aw1, kp1) GREEDY_CHUNK(5, aw1, kp1)
    GREEDY_CHUNK(6, aw1, kp1) GREEDY_CHUNK(7, aw1, kp1)
    GREEDY_CHUNK(8, aw2, kp2) GREEDY_CHUNK(9, aw2, kp2)
    GREEDY_CHUNK(10, aw2, kp2) GREEDY_CHUNK(11, aw2, kp2)
    GREEDY_CHUNK(12, aw3, kp3)
#undef GREEDY_CHUNK
    if (lane == 0) { saliveW[0] = kp0; saliveW[1] = kp1; saliveW[2] = kp2; saliveW[3] = kp3; }
  }
  __syncthreads();

  // ---- outputs: boxes | labels | scores | keep
  size_t M = (size_t)C1 * KTOP;
  float* out_boxes  = out;
  float* out_labels = out + (size_t)B * M * 4;
  float* out_scores = out_labels + (size_t)B * M;
  float* out_keep   = out_scores + (size_t)B * M;
  if (tid < KTOP) {
    size_t slot = ((size_t)b * C1 + c) * KTOP + tid;
    bool kept = (tid < valid_cnt) && ((saliveW[tid >> 6] >> (tid & 63)) & 1ULL);
    float4 bx = kept ? make_float4(bl[tid], bt[tid], br_[tid], bb_[tid])
                     : make_float4(0.f, 0.f, 0.f, 0.f);
    reinterpret_cast<float4*>(out_boxes)[slot] = bx;
    out_labels[slot] = kept ? (float)(c + 1) : 0.0f;
    out_scores[slot] = kept ? (float)exp(unflip64(skid[tid])) : 0.0f;
    out_keep[slot]   = kept ? 1.0f : 0.0f;
  }
}

extern "C" void kernel_launch(void* const* d_in, const int* in_sizes, int n_in,
                              void* d_out, int out_size, void* d_ws, size_t ws_size,
                              hipStream_t stream) {
  const float* bboxes   = (const float*)d_in[0];   // [B,4,N]
  const float* scores   = (const float*)d_in[1];   // [B,21,N]
  const float* dboxes   = (const float*)d_in[2];   // [1,N,4]
  const float* conf_th  = (const float*)d_in[3];   // [20]
  const float* nms_th   = (const float*)d_in[4];   // scalar
  const float* scale_xy = (const float*)d_in[6];   // scalar
  const float* scale_wh = (const float*)d_in[7];   // scalar

  int N = in_sizes[2] / 4;
  int B = in_sizes[0] / (4 * N);
  const int C1 = NCLS - 1;

  // workspace layout: lse (f64) | boxes (float4) | keys (u32)
  char* ws = (char*)d_ws;
  double* lse     = (double*)ws;
  float4* boxesws = (float4*)(ws + (size_t)B * N * 8);
  uint*   keys    = (uint*)  (ws + (size_t)B * N * 8 + (size_t)B * N * 16);

  int total = B * N;
  int blocksA = (total + NT - 1) / NT;
  prep_kernel<<<blocksA, NT, 0, stream>>>(
      bboxes, scores, dboxes, conf_th, scale_xy, scale_wh,
      boxesws, lse, keys, B, N);

  select_nms_kernel<<<B * C1, NT, 0, stream>>>(
      keys, scores, lse, boxesws, nms_th, (float*)d_out, B, N);
}